// Round 9
// baseline (201.679 us; speedup 1.0000x reference)
//
#include <hip/hip_runtime.h>
#include <math.h>

#define HID 128
#define INDIM 64
#define NSH 64   // pooled shadow copies

typedef unsigned int uint;
typedef unsigned short ushort;
typedef __attribute__((ext_vector_type(8))) short short8;
typedef __attribute__((ext_vector_type(4))) float f32x4;

static __device__ inline float bf2f(uint h) { return __uint_as_float(h << 16); }
static __device__ inline ushort f2bf(float f) {
    uint u = __float_as_uint(f);
    return (ushort)((u + 0x7fff + ((u >> 16) & 1)) >> 16);  // RNE
}
static __device__ inline uint packbf2(float a, float b) {
    return (uint)f2bf(a) | ((uint)f2bf(b) << 16);
}
static __device__ inline int imax(int a, int b) { return a > b ? a : b; }

static __device__ inline void init8(float* a, uint4 v, float sl) {
    a[0] = bf2f(v.x & 0xffffu) * sl; a[1] = bf2f(v.x >> 16) * sl;
    a[2] = bf2f(v.y & 0xffffu) * sl; a[3] = bf2f(v.y >> 16) * sl;
    a[4] = bf2f(v.z & 0xffffu) * sl; a[5] = bf2f(v.z >> 16) * sl;
    a[6] = bf2f(v.w & 0xffffu) * sl; a[7] = bf2f(v.w >> 16) * sl;
}
static __device__ inline void acc8(float* a, uint4 u, float f) {
    a[0] = fmaf(bf2f(u.x & 0xffffu), f, a[0]); a[1] = fmaf(bf2f(u.x >> 16), f, a[1]);
    a[2] = fmaf(bf2f(u.y & 0xffffu), f, a[2]); a[3] = fmaf(bf2f(u.y >> 16), f, a[3]);
    a[4] = fmaf(bf2f(u.z & 0xffffu), f, a[4]); a[5] = fmaf(bf2f(u.z >> 16), f, a[5]);
    a[6] = fmaf(bf2f(u.w & 0xffffu), f, a[6]); a[7] = fmaf(bf2f(u.w >> 16), f, a[7]);
}
static __device__ inline void init4(float* a, uint2 v, float sl) {
    a[0] = bf2f(v.x & 0xffffu) * sl; a[1] = bf2f(v.x >> 16) * sl;
    a[2] = bf2f(v.y & 0xffffu) * sl; a[3] = bf2f(v.y >> 16) * sl;
}
static __device__ inline void acc4(float* a, uint2 u, float f) {
    a[0] = fmaf(bf2f(u.x & 0xffffu), f, a[0]); a[1] = fmaf(bf2f(u.x >> 16), f, a[1]);
    a[2] = fmaf(bf2f(u.y & 0xffffu), f, a[2]); a[3] = fmaf(bf2f(u.y >> 16), f, a[3]);
}

// ---------------- init + casts + int32/int64 detect ----------------
// xbf is now batch-major [b][n][64c] = exact layout of x, so it's a flat cast.
__global__ __launch_bounds__(256) void k_init_cast(
    const float* __restrict__ x, const float* __restrict__ W1, const float* __restrict__ W2,
    const int* __restrict__ ei,
    uint* __restrict__ xbf, uint* __restrict__ w1t, uint* __restrict__ w2t,
    int* cnt, float* pooledS, int* flag, int N)
{
    int gid = blockIdx.x * 256 + threadIdx.x;
    int stride = gridDim.x * 256;
    if (blockIdx.x == 0) {
        __shared__ int sbad;
        if (threadIdx.x == 0) sbad = 0;
        __syncthreads();
        int bad = (ei[2 * threadIdx.x + 1] != 0) ? 1 : 0;
        if (__any(bad) && (threadIdx.x & 63) == 0) atomicOr(&sbad, 1);
        __syncthreads();
        if (threadIdx.x == 0) *flag = sbad;
    }
    int total = N * 128;  // bf16-pairs (N*4batches*32 pairs)
    for (int i = gid; i < total; i += stride)
        xbf[i] = packbf2(x[2 * (size_t)i], x[2 * (size_t)i + 1]);
    if (gid < 128 * 32) { int c = gid >> 5, k2 = gid & 31; w1t[gid] = packbf2(W1[(2 * k2) * 128 + c], W1[(2 * k2 + 1) * 128 + c]); }
    if (gid < 128 * 64) { int c = gid >> 6, k2 = gid & 63; w2t[gid] = packbf2(W2[(2 * k2) * 128 + c], W2[(2 * k2 + 1) * 128 + c]); }
    if (gid < N) cnt[gid] = 0;
    if (gid < NSH * 512) pooledS[gid] = 0.f;
}

// extract src/dst + degree count (fused)
__global__ __launch_bounds__(256) void k_edges(const int* __restrict__ ei, const int* __restrict__ flag,
                                               int* __restrict__ src, int* __restrict__ dst,
                                               int* cnt, int E) {
    int e = blockIdx.x * 256 + threadIdx.x;
    if (e >= E) return;
    int s, d;
    if (*flag) { s = ei[e]; d = ei[(size_t)E + e]; }
    else       { s = ei[2 * (size_t)e]; d = ei[2 * (size_t)E + 2 * (size_t)e]; }
    src[e] = s; dst[e] = d;
    atomicAdd(&cnt[d], 1);
}

// ---------------- parallel single-block scan: 1024 threads, shuffle-scan ----------------
__global__ __launch_bounds__(1024) void k_scan(const int* __restrict__ cnt, int* __restrict__ row_ptr,
                                               float* __restrict__ dis, int* __restrict__ fillcnt, int N) {
    __shared__ int wsum[16];
    int t = threadIdx.x;
    int chunk = (N + 1023) >> 10;
    int lo = t * chunk; if (lo > N) lo = N;
    int hi = lo + chunk; if (hi > N) hi = N;
    int s = 0;
#pragma unroll 4
    for (int i = lo; i < hi; i++) s += cnt[i];
    int lane = t & 63, wid = t >> 6;
    int v = s;
#pragma unroll
    for (int d = 1; d < 64; d <<= 1) {
        int u = __shfl_up(v, d);
        if (lane >= d) v += u;
    }
    if (lane == 63) wsum[wid] = v;
    __syncthreads();
    if (wid == 0) {
        int wv = (lane < 16) ? wsum[lane] : 0;
#pragma unroll
        for (int d = 1; d < 16; d <<= 1) {
            int u = __shfl_up(wv, d);
            if (lane >= d) wv += u;
        }
        if (lane < 16) wsum[lane] = wv;
    }
    __syncthreads();
    int base = (wid > 0 ? wsum[wid - 1] : 0) + (v - s);
    int acc = base;
#pragma unroll 4
    for (int i = lo; i < hi; i++) {
        row_ptr[i] = acc;
        int c = cnt[i];
        acc += c;
        dis[i] = rsqrtf((float)(c + 1));
        fillcnt[i] = 0;
    }
    if (t == 0) row_ptr[N] = wsum[15];
}

// CSR fill; wsrc[p] = dis[src] precomputed
__global__ __launch_bounds__(256) void k_fill(const int* __restrict__ src, const int* __restrict__ dst,
                                              const int* __restrict__ row_ptr, int* fillcnt,
                                              int* __restrict__ col, float* __restrict__ wsrc,
                                              const float* __restrict__ dis, int E) {
    int e = blockIdx.x * 256 + threadIdx.x;
    if (e >= E) return;
    int d = dst[e], s = src[e];
    int p = row_ptr[d] + atomicAdd(&fillcnt[d], 1);
    col[p] = s;
    wsrc[p] = dis[s];
}

// XCD-pinned batch mapping: batch = (bid&7)>>1 (XCD pair), j = within-batch block idx.
// Grid must be a multiple of 8 (G=1256) -> bijective (ERRATA #11 safe).
#define BATCH_MAP() \
    int bid = blockIdx.x; \
    int bq = (bid & 7) >> 1; \
    int jj = ((bid >> 3) << 1) | (bid & 1); \
    int tl = jj * 4 + w; \
    if (tl >= ntiles) return;

// ---------------- layer 1: batch-split 16-node tiles, LDS-staged W1, one barrier ----------------
// wave = one tile (16 nodes, batch bq). Gather: 4 phases x 4 lane-group chains (16 lanes/chain).
__global__ __launch_bounds__(256, 4) void k_l1(
    const uint* __restrict__ xbf, const int* __restrict__ rp, const int* __restrict__ col,
    const float* __restrict__ wsrc, const float* __restrict__ dis,
    const uint* __restrict__ w1t, const float* __restrict__ b1,
    uint* __restrict__ x1, int N, int ntiles)
{
    __shared__ __align__(16) char sW[16384];      // W1T swizzled: 128c x 64k bf16
    __shared__ __align__(16) char sXa[4][2048];   // wave-private 16 rows x 128B
    int t = threadIdx.x, w = t >> 6, l = t & 63;
    int g = l >> 4, row = l & 15;
    for (int i = t; i < 1024; i += 256) {
        int c = i >> 3, ch = i & 7;
        *(uint4*)(sW + c * 128 + ((ch ^ (c & 7)) << 4)) = *(const uint4*)(w1t + c * 32 + ch * 4);
    }
    __syncthreads();  // only barrier
    BATCH_MAP();
    char* sX = sXa[w];
    const uint2* xb = (const uint2*)xbf + (size_t)bq * N * 16;  // row = 16 uint2 = 128B
    int n0 = tl * 16;

#pragma unroll
    for (int p = 0; p < 4; p++) {
        int node = n0 + p * 4 + g;       // g = chain (lane group)
        float dn = dis[node];
        int beg = rp[node], end = rp[node + 1];
        int len = end - beg;
        float ac[4];
        init4(ac, xb[(size_t)node * 16 + row], dn * dn);
        int mx = len;
        mx = imax(mx, __shfl_xor(mx, 16));
        mx = imax(mx, __shfl_xor(mx, 32));
        for (int i = 0; i < mx; i += 2) {
            int e0 = beg + i, e1 = e0 + 1;
            bool a0 = i < len, a1 = i + 1 < len;
            uint2 u0, u1; float f0 = 0.f, f1 = 0.f;
            if (a0) { int s = col[e0]; f0 = wsrc[e0] * dn; u0 = xb[(size_t)s * 16 + row]; }
            if (a1) { int s = col[e1]; f1 = wsrc[e1] * dn; u1 = xb[(size_t)s * 16 + row]; }
            if (a0) acc4(ac, u0, f0);
            if (a1) acc4(ac, u1, f1);
        }
        int r = p * 4 + g;
        uint2 pk; pk.x = packbf2(ac[0], ac[1]); pk.y = packbf2(ac[2], ac[3]);
        *(uint2*)(sX + r * 128 + (((row >> 1) ^ (r & 7)) << 4) + ((row & 1) << 3)) = pk;
    }
    int ro0 = row * 128 + ((g ^ (row & 7)) << 4);
    int ro1 = row * 128 + (((4 + g) ^ (row & 7)) << 4);
    short8 xf0 = *(const short8*)(sX + ro0);
    short8 xf1 = *(const short8*)(sX + ro1);
    size_t rbase = ((size_t)bq * N + n0 + row) * 32;  // x1 batch-major, row = 32 uint2 = 256B
#pragma unroll
    for (int q = 0; q < 8; q++) {
        f32x4 a = {0.f, 0.f, 0.f, 0.f};
        const char* wb = sW + q * 2048;
        a = __builtin_amdgcn_mfma_f32_16x16x32_bf16(*(const short8*)(wb + ro0), xf0, a, 0, 0, 0);
        a = __builtin_amdgcn_mfma_f32_16x16x32_bf16(*(const short8*)(wb + ro1), xf1, a, 0, 0, 0);
        float4 bb = *(const float4*)(b1 + q * 16 + g * 4);
        uint2 o;
        o.x = packbf2(fmaxf(a.x + bb.x, 0.f), fmaxf(a.y + bb.y, 0.f));
        o.y = packbf2(fmaxf(a.z + bb.z, 0.f), fmaxf(a.w + bb.w, 0.f));
        ((uint2*)x1)[rbase + q * 4 + g] = o;
    }
}

// ---------------- layer 2: batch-split 16-node tiles, W2 from global/L1, barrier-free, fused pool ----------------
__global__ __launch_bounds__(256, 6) void k_l2(
    const uint* __restrict__ x1, const int* __restrict__ rp, const int* __restrict__ col,
    const float* __restrict__ wsrc, const float* __restrict__ dis,
    const uint* __restrict__ w2t, const float* __restrict__ b2,
    float* __restrict__ pooledS, int N, int ntiles, float invN)
{
    __shared__ __align__(16) char sXa[4][4096];   // wave-private 16 rows x 256B, swizzled
    int t = threadIdx.x, w = t >> 6, l = t & 63;
    int g = l >> 4, row = l & 15;
    BATCH_MAP();
    char* sX = sXa[w];
    const uint4* xb = (const uint4*)x1 + (size_t)bq * N * 16;  // row = 16 uint4 = 256B
    int n0 = tl * 16;

#pragma unroll
    for (int p = 0; p < 4; p++) {
        int node = n0 + p * 4 + g;
        float dn = dis[node];
        int beg = rp[node], end = rp[node + 1];
        int len = end - beg;
        float ac[8];
        init8(ac, xb[(size_t)node * 16 + row], dn * dn);
        int mx = len;
        mx = imax(mx, __shfl_xor(mx, 16));
        mx = imax(mx, __shfl_xor(mx, 32));
        for (int i = 0; i < mx; i += 2) {
            int e0 = beg + i, e1 = e0 + 1;
            bool a0 = i < len, a1 = i + 1 < len;
            uint4 u0, u1; float f0 = 0.f, f1 = 0.f;
            if (a0) { int s = col[e0]; f0 = wsrc[e0] * dn; u0 = xb[(size_t)s * 16 + row]; }
            if (a1) { int s = col[e1]; f1 = wsrc[e1] * dn; u1 = xb[(size_t)s * 16 + row]; }
            if (a0) acc8(ac, u0, f0);
            if (a1) acc8(ac, u1, f1);
        }
        int r = p * 4 + g;
        uint4 pk;
        pk.x = packbf2(ac[0], ac[1]); pk.y = packbf2(ac[2], ac[3]);
        pk.z = packbf2(ac[4], ac[5]); pk.w = packbf2(ac[6], ac[7]);
        *(uint4*)(sX + r * 256 + ((row ^ (r & 7)) << 4)) = pk;
    }
    short8 xf[4];
#pragma unroll
    for (int ks = 0; ks < 4; ks++)
        xf[ks] = *(const short8*)(sX + row * 256 + (((ks * 4 + g) ^ (row & 7)) << 4));
    int sh = tl & (NSH - 1);
    float* pd = pooledS + (size_t)sh * 512 + bq * 128;
#pragma unroll 2
    for (int q = 0; q < 8; q++) {
        const uint* wq = w2t + (q * 16 + row) * 64 + g * 4;   // W2T 32KB, L1-hot
        f32x4 a = {0.f, 0.f, 0.f, 0.f};
        a = __builtin_amdgcn_mfma_f32_16x16x32_bf16(*(const short8*)(wq),      xf[0], a, 0, 0, 0);
        a = __builtin_amdgcn_mfma_f32_16x16x32_bf16(*(const short8*)(wq + 16), xf[1], a, 0, 0, 0);
        a = __builtin_amdgcn_mfma_f32_16x16x32_bf16(*(const short8*)(wq + 32), xf[2], a, 0, 0, 0);
        a = __builtin_amdgcn_mfma_f32_16x16x32_bf16(*(const short8*)(wq + 48), xf[3], a, 0, 0, 0);
        float4 bb = *(const float4*)(b2 + q * 16 + g * 4);
        float v0 = fmaxf(a.x + bb.x, 0.f);
        float v1 = fmaxf(a.y + bb.y, 0.f);
        float v2 = fmaxf(a.z + bb.z, 0.f);
        float v3 = fmaxf(a.w + bb.w, 0.f);
        // sum over the tile's 16 nodes (D cols = l&15)
        v0 += __shfl_xor(v0, 1); v0 += __shfl_xor(v0, 2); v0 += __shfl_xor(v0, 4); v0 += __shfl_xor(v0, 8);
        v1 += __shfl_xor(v1, 1); v1 += __shfl_xor(v1, 2); v1 += __shfl_xor(v1, 4); v1 += __shfl_xor(v1, 8);
        v2 += __shfl_xor(v2, 1); v2 += __shfl_xor(v2, 2); v2 += __shfl_xor(v2, 4); v2 += __shfl_xor(v2, 8);
        v3 += __shfl_xor(v3, 1); v3 += __shfl_xor(v3, 2); v3 += __shfl_xor(v3, 4); v3 += __shfl_xor(v3, 8);
        if (row == 0) {
            atomicAdd(&pd[q * 16 + g * 4 + 0], v0 * invN);
            atomicAdd(&pd[q * 16 + g * 4 + 1], v1 * invN);
            atomicAdd(&pd[q * 16 + g * 4 + 2], v2 * invN);
            atomicAdd(&pd[q * 16 + g * 4 + 3], v3 * invN);
        }
    }
}

// ---------------- head: parallel shadow reduce + GEMV ----------------
__global__ __launch_bounds__(512) void k_head(const float* __restrict__ pooledS, const float* __restrict__ af,
                                              const float* __restrict__ fcw, const float* __restrict__ fcb,
                                              const float* __restrict__ sig, float* __restrict__ out, int B) {
    __shared__ float pool[512];
    int t = threadIdx.x;
    float s = 0.f;
#pragma unroll 8
    for (int sh = 0; sh < NSH; sh++) s += pooledS[sh * 512 + t];
    pool[t] = s;
    __syncthreads();
    if (t >= B * 16) return;
    int b = t >> 4, o = t & 15;
    float acc = fcb[o];
    for (int c = 0; c < HID; c++) acc = fmaf(pool[b * 128 + c], fcw[c * 16 + o], acc);
    acc = fmaf(af[b], fcw[HID * 16 + o], acc);
    out[t] = acc;
    out[B * 16 + t] = expf(sig[o]);
}

// ---------------- launch ----------------

extern "C" void kernel_launch(void* const* d_in, const int* in_sizes, int n_in,
                              void* d_out, int out_size, void* d_ws, size_t ws_size,
                              hipStream_t stream) {
    const float* x   = (const float*)d_in[0];
    const float* af  = (const float*)d_in[1];
    const int*   ei  = (const int*)d_in[2];
    const float* W1  = (const float*)d_in[3];
    const float* b1  = (const float*)d_in[4];
    const float* W2  = (const float*)d_in[5];
    const float* b2  = (const float*)d_in[6];
    const float* fcw = (const float*)d_in[7];
    const float* fcb = (const float*)d_in[8];
    const float* sig = (const float*)d_in[9];

    int B = in_sizes[1];                 // 4
    int E = in_sizes[2] / 2;             // 320000
    int N = in_sizes[0] / (B * INDIM);   // 20000
    int ntiles = N / 16;                 // 1250 node-tiles per batch

    char* p = (char*)d_ws;
    auto alloc = [&](size_t bytes) { void* r = (void*)p; p += (bytes + 255) & ~(size_t)255; return r; };
    int*    cnt     = (int*)alloc((size_t)N * 4);
    int*    fillcnt = (int*)alloc((size_t)N * 4);
    int*    row_ptr = (int*)alloc((size_t)(N + 1) * 4);
    int*    colA    = (int*)alloc((size_t)E * 4);
    int*    srcA    = (int*)alloc((size_t)E * 4);
    int*    dstA    = (int*)alloc((size_t)E * 4);
    float*  wsrcA   = (float*)alloc((size_t)E * 4);
    float*  dis     = (float*)alloc((size_t)N * 4);
    float*  pooledS = (float*)alloc((size_t)NSH * 512 * 4);
    int*    flag    = (int*)alloc(256);
    uint*   xbf     = (uint*)alloc((size_t)N * 128 * 4);      // bf16 [b][n][64c] (2.56MB/batch)
    uint*   x1      = (uint*)alloc((size_t)N * 4 * 64 * 4);   // bf16 [b][n][128c] (5.125MB/batch)
    uint*   w1t     = (uint*)alloc((size_t)128 * 32 * 4);     // bf16 [128c][64k]
    uint*   w2t     = (uint*)alloc((size_t)128 * 64 * 4);     // bf16 [128c][128k]
    (void)ws_size;

    int gE = (E + 255) / 256;
    // blocks: per batch ceil(1250/4)=313 -> 8*ceil(313*... -> G=1256 (multiple of 8, bijective map)
    int gL = 8 * ((((ntiles + 3) / 4) + 1) / 2);   // 8 * 157 = 1256

    k_init_cast<<<2048, 256, 0, stream>>>(x, W1, W2, ei, xbf, w1t, w2t, cnt, pooledS, flag, N);
    k_edges<<<gE, 256, 0, stream>>>(ei, flag, srcA, dstA, cnt, E);
    k_scan<<<1, 1024, 0, stream>>>(cnt, row_ptr, dis, fillcnt, N);
    k_fill<<<gE, 256, 0, stream>>>(srcA, dstA, row_ptr, fillcnt, colA, wsrcA, dis, E);

    k_l1<<<gL, 256, 0, stream>>>(xbf, row_ptr, colA, wsrcA, dis, w1t, b1, x1, N, ntiles);
    k_l2<<<gL, 256, 0, stream>>>(x1, row_ptr, colA, wsrcA, dis, w2t, b2, pooledS, N, ntiles, 1.0f / (float)N);

    k_head<<<1, 512, 0, stream>>>(pooledS, af, fcw, fcb, sig, (float*)d_out, B);
}

// Round 10
// 190.055 us; speedup vs baseline: 1.0612x; 1.0612x over previous
//
#include <hip/hip_runtime.h>
#include <math.h>

#define HID 128
#define INDIM 64
#define NSH 64   // pooled shadow copies

typedef unsigned int uint;
typedef unsigned short ushort;
typedef __attribute__((ext_vector_type(8))) short short8;
typedef __attribute__((ext_vector_type(4))) float f32x4;

static __device__ inline float bf2f(uint h) { return __uint_as_float(h << 16); }
static __device__ inline ushort f2bf(float f) {
    uint u = __float_as_uint(f);
    return (ushort)((u + 0x7fff + ((u >> 16) & 1)) >> 16);  // RNE
}
static __device__ inline uint packbf2(float a, float b) {
    return (uint)f2bf(a) | ((uint)f2bf(b) << 16);
}
static __device__ inline int imax(int a, int b) { return a > b ? a : b; }

static __device__ inline void init8(float* a, uint4 v, float sl) {
    a[0] = bf2f(v.x & 0xffffu) * sl; a[1] = bf2f(v.x >> 16) * sl;
    a[2] = bf2f(v.y & 0xffffu) * sl; a[3] = bf2f(v.y >> 16) * sl;
    a[4] = bf2f(v.z & 0xffffu) * sl; a[5] = bf2f(v.z >> 16) * sl;
    a[6] = bf2f(v.w & 0xffffu) * sl; a[7] = bf2f(v.w >> 16) * sl;
}
static __device__ inline void acc8(float* a, uint4 u, float f) {
    a[0] = fmaf(bf2f(u.x & 0xffffu), f, a[0]); a[1] = fmaf(bf2f(u.x >> 16), f, a[1]);
    a[2] = fmaf(bf2f(u.y & 0xffffu), f, a[2]); a[3] = fmaf(bf2f(u.y >> 16), f, a[3]);
    a[4] = fmaf(bf2f(u.z & 0xffffu), f, a[4]); a[5] = fmaf(bf2f(u.z >> 16), f, a[5]);
    a[6] = fmaf(bf2f(u.w & 0xffffu), f, a[6]); a[7] = fmaf(bf2f(u.w >> 16), f, a[7]);
}
static __device__ inline void init4(float* a, uint2 v, float sl) {
    a[0] = bf2f(v.x & 0xffffu) * sl; a[1] = bf2f(v.x >> 16) * sl;
    a[2] = bf2f(v.y & 0xffffu) * sl; a[3] = bf2f(v.y >> 16) * sl;
}
static __device__ inline void acc4(float* a, uint2 u, float f) {
    a[0] = fmaf(bf2f(u.x & 0xffffu), f, a[0]); a[1] = fmaf(bf2f(u.x >> 16), f, a[1]);
    a[2] = fmaf(bf2f(u.y & 0xffffu), f, a[2]); a[3] = fmaf(bf2f(u.y >> 16), f, a[3]);
}

// ---------------- init + casts + int32/int64 detect ----------------
// xbf batch-major [b][n][64c] = exact layout of x -> flat cast.
__global__ __launch_bounds__(256) void k_init_cast(
    const float* __restrict__ x, const float* __restrict__ W1, const float* __restrict__ W2,
    const int* __restrict__ ei,
    uint* __restrict__ xbf, uint* __restrict__ w1t, uint* __restrict__ w2t,
    int* cnt, float* pooledS, int* flag, int N)
{
    int gid = blockIdx.x * 256 + threadIdx.x;
    int stride = gridDim.x * 256;
    if (blockIdx.x == 0) {
        __shared__ int sbad;
        if (threadIdx.x == 0) sbad = 0;
        __syncthreads();
        int bad = (ei[2 * threadIdx.x + 1] != 0) ? 1 : 0;
        if (__any(bad) && (threadIdx.x & 63) == 0) atomicOr(&sbad, 1);
        __syncthreads();
        if (threadIdx.x == 0) *flag = sbad;
    }
    int total = N * 128;  // bf16-pairs
    for (int i = gid; i < total; i += stride)
        xbf[i] = packbf2(x[2 * (size_t)i], x[2 * (size_t)i + 1]);
    if (gid < 128 * 32) { int c = gid >> 5, k2 = gid & 31; w1t[gid] = packbf2(W1[(2 * k2) * 128 + c], W1[(2 * k2 + 1) * 128 + c]); }
    if (gid < 128 * 64) { int c = gid >> 6, k2 = gid & 63; w2t[gid] = packbf2(W2[(2 * k2) * 128 + c], W2[(2 * k2 + 1) * 128 + c]); }
    if (gid < N) cnt[gid] = 0;
    if (gid < NSH * 512) pooledS[gid] = 0.f;
}

// extract src/dst + degree count (fused)
__global__ __launch_bounds__(256) void k_edges(const int* __restrict__ ei, const int* __restrict__ flag,
                                               int* __restrict__ src, int* __restrict__ dst,
                                               int* cnt, int E) {
    int e = blockIdx.x * 256 + threadIdx.x;
    if (e >= E) return;
    int s, d;
    if (*flag) { s = ei[e]; d = ei[(size_t)E + e]; }
    else       { s = ei[2 * (size_t)e]; d = ei[2 * (size_t)E + 2 * (size_t)e]; }
    src[e] = s; dst[e] = d;
    atomicAdd(&cnt[d], 1);
}

// ---------------- parallel single-block scan: 1024 threads, shuffle-scan ----------------
__global__ __launch_bounds__(1024) void k_scan(const int* __restrict__ cnt, int* __restrict__ row_ptr,
                                               float* __restrict__ dis, int* __restrict__ fillcnt, int N) {
    __shared__ int wsum[16];
    int t = threadIdx.x;
    int chunk = (N + 1023) >> 10;
    int lo = t * chunk; if (lo > N) lo = N;
    int hi = lo + chunk; if (hi > N) hi = N;
    int s = 0;
#pragma unroll 4
    for (int i = lo; i < hi; i++) s += cnt[i];
    int lane = t & 63, wid = t >> 6;
    int v = s;
#pragma unroll
    for (int d = 1; d < 64; d <<= 1) {
        int u = __shfl_up(v, d);
        if (lane >= d) v += u;
    }
    if (lane == 63) wsum[wid] = v;
    __syncthreads();
    if (wid == 0) {
        int wv = (lane < 16) ? wsum[lane] : 0;
#pragma unroll
        for (int d = 1; d < 16; d <<= 1) {
            int u = __shfl_up(wv, d);
            if (lane >= d) wv += u;
        }
        if (lane < 16) wsum[lane] = wv;
    }
    __syncthreads();
    int base = (wid > 0 ? wsum[wid - 1] : 0) + (v - s);
    int acc = base;
#pragma unroll 4
    for (int i = lo; i < hi; i++) {
        row_ptr[i] = acc;
        int c = cnt[i];
        acc += c;
        dis[i] = rsqrtf((float)(c + 1));
        fillcnt[i] = 0;
    }
    if (t == 0) row_ptr[N] = wsum[15];
}

// CSR fill; wsrc[p] = dis[src] precomputed
__global__ __launch_bounds__(256) void k_fill(const int* __restrict__ src, const int* __restrict__ dst,
                                              const int* __restrict__ row_ptr, int* fillcnt,
                                              int* __restrict__ col, float* __restrict__ wsrc,
                                              const float* __restrict__ dis, int E) {
    int e = blockIdx.x * 256 + threadIdx.x;
    if (e >= E) return;
    int d = dst[e], s = src[e];
    int p = row_ptr[d] + atomicAdd(&fillcnt[d], 1);
    col[p] = s;
    wsrc[p] = dis[s];
}

// XCD-pinned batch mapping: batch = (bid&7)>>1 (XCD pair). G multiple of 8 -> bijective.
#define BATCH_MAP() \
    int bid = blockIdx.x; \
    int bq = (bid & 7) >> 1; \
    int jj = ((bid >> 3) << 1) | (bid & 1); \
    int tl = jj * 4 + w; \
    if (tl >= ntiles) return;

// Branch-free gather chain setup: all loads unconditional (clamped), weights zeroed OOB.
// 4 edges in flight per lane (r5-proven ILP shape), no exec-mask branches (r9's VGPR-28 trap).

// ---------------- layer 1: batch-split 16-node tiles, LDS-staged W1, one barrier ----------------
__global__ __launch_bounds__(256, 4) void k_l1(
    const uint* __restrict__ xbf, const int* __restrict__ rp, const int* __restrict__ col,
    const float* __restrict__ wsrc, const float* __restrict__ dis,
    const uint* __restrict__ w1t, const float* __restrict__ b1,
    uint* __restrict__ x1, int N, int ntiles)
{
    __shared__ __align__(16) char sW[16384];      // W1T swizzled: 128c x 64k bf16
    __shared__ __align__(16) char sXa[4][2048];   // wave-private 16 rows x 128B
    int t = threadIdx.x, w = t >> 6, l = t & 63;
    int g = l >> 4, row = l & 15;
    for (int i = t; i < 1024; i += 256) {
        int c = i >> 3, ch = i & 7;
        *(uint4*)(sW + c * 128 + ((ch ^ (c & 7)) << 4)) = *(const uint4*)(w1t + c * 32 + ch * 4);
    }
    __syncthreads();  // only barrier
    BATCH_MAP();
    char* sX = sXa[w];
    const uint2* xb = (const uint2*)xbf + (size_t)bq * N * 16;  // row = 16 uint2 = 128B
    int n0 = tl * 16;

#pragma unroll
    for (int p = 0; p < 4; p++) {
        int node = n0 + p * 4 + g;       // g = chain (16-lane group)
        float dn = dis[node];
        int beg = rp[node], end = rp[node + 1];
        int len = end - beg;
        float ac[4];
        init4(ac, xb[(size_t)node * 16 + row], dn * dn);
        int mx = imax(len, __shfl_xor(len, 16));
        mx = imax(mx, __shfl_xor(mx, 32));
        int base = (len > 0) ? beg : 0;  // safe base for clamped loads
        for (int i = 0; i < mx; i += 4) {
            int i0 = (i < len) ? i : 0;
            int i1 = (i + 1 < len) ? i + 1 : 0;
            int i2 = (i + 2 < len) ? i + 2 : 0;
            int i3 = (i + 3 < len) ? i + 3 : 0;
            int e0 = base + i0, e1 = base + i1, e2 = base + i2, e3 = base + i3;
            float f0 = (i < len) ? wsrc[e0] * dn : 0.f;
            float f1 = (i + 1 < len) ? wsrc[e1] * dn : 0.f;
            float f2 = (i + 2 < len) ? wsrc[e2] * dn : 0.f;
            float f3 = (i + 3 < len) ? wsrc[e3] * dn : 0.f;
            int s0 = col[e0], s1 = col[e1], s2 = col[e2], s3 = col[e3];
            uint2 u0 = xb[(size_t)s0 * 16 + row];
            uint2 u1 = xb[(size_t)s1 * 16 + row];
            uint2 u2 = xb[(size_t)s2 * 16 + row];
            uint2 u3 = xb[(size_t)s3 * 16 + row];
            acc4(ac, u0, f0);
            acc4(ac, u1, f1);
            acc4(ac, u2, f2);
            acc4(ac, u3, f3);
        }
        int r = p * 4 + g;
        uint2 pk; pk.x = packbf2(ac[0], ac[1]); pk.y = packbf2(ac[2], ac[3]);
        *(uint2*)(sX + r * 128 + (((row >> 1) ^ (r & 7)) << 4) + ((row & 1) << 3)) = pk;
    }
    int ro0 = row * 128 + ((g ^ (row & 7)) << 4);
    int ro1 = row * 128 + (((4 + g) ^ (row & 7)) << 4);
    short8 xf0 = *(const short8*)(sX + ro0);
    short8 xf1 = *(const short8*)(sX + ro1);
    size_t rbase = ((size_t)bq * N + n0 + row) * 32;  // x1 batch-major, row = 32 uint2 = 256B
#pragma unroll
    for (int q = 0; q < 8; q++) {
        f32x4 a = {0.f, 0.f, 0.f, 0.f};
        const char* wb = sW + q * 2048;
        a = __builtin_amdgcn_mfma_f32_16x16x32_bf16(*(const short8*)(wb + ro0), xf0, a, 0, 0, 0);
        a = __builtin_amdgcn_mfma_f32_16x16x32_bf16(*(const short8*)(wb + ro1), xf1, a, 0, 0, 0);
        float4 bb = *(const float4*)(b1 + q * 16 + g * 4);
        uint2 o;
        o.x = packbf2(fmaxf(a.x + bb.x, 0.f), fmaxf(a.y + bb.y, 0.f));
        o.y = packbf2(fmaxf(a.z + bb.z, 0.f), fmaxf(a.w + bb.w, 0.f));
        ((uint2*)x1)[rbase + q * 4 + g] = o;
    }
}

// ---------------- layer 2: batch-split 16-node tiles, W2 from global/L1, barrier-free, fused pool ----------------
__global__ __launch_bounds__(256, 4) void k_l2(
    const uint* __restrict__ x1, const int* __restrict__ rp, const int* __restrict__ col,
    const float* __restrict__ wsrc, const float* __restrict__ dis,
    const uint* __restrict__ w2t, const float* __restrict__ b2,
    float* __restrict__ pooledS, int N, int ntiles, float invN)
{
    __shared__ __align__(16) char sXa[4][4096];   // wave-private 16 rows x 256B, swizzled
    int t = threadIdx.x, w = t >> 6, l = t & 63;
    int g = l >> 4, row = l & 15;
    BATCH_MAP();
    char* sX = sXa[w];
    const uint4* xb = (const uint4*)x1 + (size_t)bq * N * 16;  // row = 16 uint4 = 256B
    int n0 = tl * 16;

#pragma unroll
    for (int p = 0; p < 4; p++) {
        int node = n0 + p * 4 + g;
        float dn = dis[node];
        int beg = rp[node], end = rp[node + 1];
        int len = end - beg;
        float ac[8];
        init8(ac, xb[(size_t)node * 16 + row], dn * dn);
        int mx = imax(len, __shfl_xor(len, 16));
        mx = imax(mx, __shfl_xor(mx, 32));
        int base = (len > 0) ? beg : 0;
        for (int i = 0; i < mx; i += 4) {
            int i0 = (i < len) ? i : 0;
            int i1 = (i + 1 < len) ? i + 1 : 0;
            int i2 = (i + 2 < len) ? i + 2 : 0;
            int i3 = (i + 3 < len) ? i + 3 : 0;
            int e0 = base + i0, e1 = base + i1, e2 = base + i2, e3 = base + i3;
            float f0 = (i < len) ? wsrc[e0] * dn : 0.f;
            float f1 = (i + 1 < len) ? wsrc[e1] * dn : 0.f;
            float f2 = (i + 2 < len) ? wsrc[e2] * dn : 0.f;
            float f3 = (i + 3 < len) ? wsrc[e3] * dn : 0.f;
            int s0 = col[e0], s1 = col[e1], s2 = col[e2], s3 = col[e3];
            uint4 u0 = xb[(size_t)s0 * 16 + row];
            uint4 u1 = xb[(size_t)s1 * 16 + row];
            uint4 u2 = xb[(size_t)s2 * 16 + row];
            uint4 u3 = xb[(size_t)s3 * 16 + row];
            acc8(ac, u0, f0);
            acc8(ac, u1, f1);
            acc8(ac, u2, f2);
            acc8(ac, u3, f3);
        }
        int r = p * 4 + g;
        uint4 pk;
        pk.x = packbf2(ac[0], ac[1]); pk.y = packbf2(ac[2], ac[3]);
        pk.z = packbf2(ac[4], ac[5]); pk.w = packbf2(ac[6], ac[7]);
        *(uint4*)(sX + r * 256 + ((row ^ (r & 7)) << 4)) = pk;
    }
    short8 xf[4];
#pragma unroll
    for (int ks = 0; ks < 4; ks++)
        xf[ks] = *(const short8*)(sX + row * 256 + (((ks * 4 + g) ^ (row & 7)) << 4));
    int sh = tl & (NSH - 1);
    float* pd = pooledS + (size_t)sh * 512 + bq * 128;
#pragma unroll 2
    for (int q = 0; q < 8; q++) {
        const uint* wq = w2t + (q * 16 + row) * 64 + g * 4;   // W2T 32KB, L1-hot
        f32x4 a = {0.f, 0.f, 0.f, 0.f};
        a = __builtin_amdgcn_mfma_f32_16x16x32_bf16(*(const short8*)(wq),      xf[0], a, 0, 0, 0);
        a = __builtin_amdgcn_mfma_f32_16x16x32_bf16(*(const short8*)(wq + 16), xf[1], a, 0, 0, 0);
        a = __builtin_amdgcn_mfma_f32_16x16x32_bf16(*(const short8*)(wq + 32), xf[2], a, 0, 0, 0);
        a = __builtin_amdgcn_mfma_f32_16x16x32_bf16(*(const short8*)(wq + 48), xf[3], a, 0, 0, 0);
        float4 bb = *(const float4*)(b2 + q * 16 + g * 4);
        float v0 = fmaxf(a.x + bb.x, 0.f);
        float v1 = fmaxf(a.y + bb.y, 0.f);
        float v2 = fmaxf(a.z + bb.z, 0.f);
        float v3 = fmaxf(a.w + bb.w, 0.f);
        // sum over the tile's 16 nodes (D cols = l&15)
        v0 += __shfl_xor(v0, 1); v0 += __shfl_xor(v0, 2); v0 += __shfl_xor(v0, 4); v0 += __shfl_xor(v0, 8);
        v1 += __shfl_xor(v1, 1); v1 += __shfl_xor(v1, 2); v1 += __shfl_xor(v1, 4); v1 += __shfl_xor(v1, 8);
        v2 += __shfl_xor(v2, 1); v2 += __shfl_xor(v2, 2); v2 += __shfl_xor(v2, 4); v2 += __shfl_xor(v2, 8);
        v3 += __shfl_xor(v3, 1); v3 += __shfl_xor(v3, 2); v3 += __shfl_xor(v3, 4); v3 += __shfl_xor(v3, 8);
        if (row == 0) {
            atomicAdd(&pd[q * 16 + g * 4 + 0], v0 * invN);
            atomicAdd(&pd[q * 16 + g * 4 + 1], v1 * invN);
            atomicAdd(&pd[q * 16 + g * 4 + 2], v2 * invN);
            atomicAdd(&pd[q * 16 + g * 4 + 3], v3 * invN);
        }
    }
}

// ---------------- head: parallel shadow reduce + GEMV ----------------
__global__ __launch_bounds__(512) void k_head(const float* __restrict__ pooledS, const float* __restrict__ af,
                                              const float* __restrict__ fcw, const float* __restrict__ fcb,
                                              const float* __restrict__ sig, float* __restrict__ out, int B) {
    __shared__ float pool[512];
    int t = threadIdx.x;
    float s = 0.f;
#pragma unroll 8
    for (int sh = 0; sh < NSH; sh++) s += pooledS[sh * 512 + t];
    pool[t] = s;
    __syncthreads();
    if (t >= B * 16) return;
    int b = t >> 4, o = t & 15;
    float acc = fcb[o];
    for (int c = 0; c < HID; c++) acc = fmaf(pool[b * 128 + c], fcw[c * 16 + o], acc);
    acc = fmaf(af[b], fcw[HID * 16 + o], acc);
    out[t] = acc;
    out[B * 16 + t] = expf(sig[o]);
}

// ---------------- launch ----------------

extern "C" void kernel_launch(void* const* d_in, const int* in_sizes, int n_in,
                              void* d_out, int out_size, void* d_ws, size_t ws_size,
                              hipStream_t stream) {
    const float* x   = (const float*)d_in[0];
    const float* af  = (const float*)d_in[1];
    const int*   ei  = (const int*)d_in[2];
    const float* W1  = (const float*)d_in[3];
    const float* b1  = (const float*)d_in[4];
    const float* W2  = (const float*)d_in[5];
    const float* b2  = (const float*)d_in[6];
    const float* fcw = (const float*)d_in[7];
    const float* fcb = (const float*)d_in[8];
    const float* sig = (const float*)d_in[9];

    int B = in_sizes[1];                 // 4
    int E = in_sizes[2] / 2;             // 320000
    int N = in_sizes[0] / (B * INDIM);   // 20000
    int ntiles = N / 16;                 // 1250 node-tiles per batch

    char* p = (char*)d_ws;
    auto alloc = [&](size_t bytes) { void* r = (void*)p; p += (bytes + 255) & ~(size_t)255; return r; };
    int*    cnt     = (int*)alloc((size_t)N * 4);
    int*    fillcnt = (int*)alloc((size_t)N * 4);
    int*    row_ptr = (int*)alloc((size_t)(N + 1) * 4);
    int*    colA    = (int*)alloc((size_t)E * 4);
    int*    srcA    = (int*)alloc((size_t)E * 4);
    int*    dstA    = (int*)alloc((size_t)E * 4);
    float*  wsrcA   = (float*)alloc((size_t)E * 4);
    float*  dis     = (float*)alloc((size_t)N * 4);
    float*  pooledS = (float*)alloc((size_t)NSH * 512 * 4);
    int*    flag    = (int*)alloc(256);
    uint*   xbf     = (uint*)alloc((size_t)N * 128 * 4);      // bf16 [b][n][64c] (2.56MB/batch)
    uint*   x1      = (uint*)alloc((size_t)N * 4 * 64 * 4);   // bf16 [b][n][128c] (5.125MB/batch)
    uint*   w1t     = (uint*)alloc((size_t)128 * 32 * 4);     // bf16 [128c][64k]
    uint*   w2t     = (uint*)alloc((size_t)128 * 64 * 4);     // bf16 [128c][128k]
    (void)ws_size;

    int gE = (E + 255) / 256;
    int gL = 8 * ((((ntiles + 3) / 4) + 1) / 2);   // 1256, multiple of 8 (bijective XCD map)

    k_init_cast<<<2048, 256, 0, stream>>>(x, W1, W2, ei, xbf, w1t, w2t, cnt, pooledS, flag, N);
    k_edges<<<gE, 256, 0, stream>>>(ei, flag, srcA, dstA, cnt, E);
    k_scan<<<1, 1024, 0, stream>>>(cnt, row_ptr, dis, fillcnt, N);
    k_fill<<<gE, 256, 0, stream>>>(srcA, dstA, row_ptr, fillcnt, colA, wsrcA, dis, E);

    k_l1<<<gL, 256, 0, stream>>>(xbf, row_ptr, colA, wsrcA, dis, w1t, b1, x1, N, ntiles);
    k_l2<<<gL, 256, 0, stream>>>(x1, row_ptr, colA, wsrcA, dis, w2t, b2, pooledS, N, ntiles, 1.0f / (float)N);

    k_head<<<1, 512, 0, stream>>>(pooledS, af, fcw, fcb, sig, (float*)d_out, B);
}